// Round 1
// baseline (158.480 us; speedup 1.0000x reference)
//
#include <hip/hip_runtime.h>
#include <hip/hip_bf16.h>
#include <math.h>

#define D_DIM 512
#define TM    128
#define TN    256

typedef int i32x4 __attribute__((ext_vector_type(4)));
typedef unsigned long long u64;

// ---- helpers ---------------------------------------------------------------

__device__ inline u64 shfl_xor_u64(u64 x, int m) {
    int lo = __shfl_xor((int)(unsigned)(x & 0xFFFFFFFFull), m, 64);
    int hi = __shfl_xor((int)(unsigned)(x >> 32), m, 64);
    return ((u64)(unsigned)hi << 32) | (u64)(unsigned)lo;
}

// ---- kernel 1: row L2-normalize -> int8 (x127), init best/acc/cnt ----------

__global__ __launch_bounds__(256) void normalize_rows(
        const float* __restrict__ in, unsigned char* __restrict__ xb,
        float* __restrict__ inv_norm, u64* __restrict__ best,
        float* __restrict__ acc, int* __restrict__ cnt) {
    const int row  = blockIdx.x * 4 + (threadIdx.x >> 6);
    const int lane = threadIdx.x & 63;
    if (blockIdx.x == 0 && threadIdx.x == 0) { acc[0] = 0.f; cnt[0] = 0; }
    const float4* rp = (const float4*)(in + (size_t)row * D_DIM) + lane * 2;
    float4 a = rp[0], b = rp[1];
    float s = a.x*a.x + a.y*a.y + a.z*a.z + a.w*a.w
            + b.x*b.x + b.y*b.y + b.z*b.z + b.w*b.w;
    #pragma unroll
    for (int m = 1; m <= 32; m <<= 1) s += __shfl_xor(s, m, 64);
    float inv = 1.0f / fmaxf(sqrtf(s), 1e-8f);
    if (lane == 0) {
        inv_norm[row] = inv;
        best[row] = 0ull;   // below any real packed key
    }
    float sc = inv * 127.0f;   // int8 symmetric quant; |x_norm|<=1 -> no clamp
    int q0 = __float2int_rn(a.x*sc), q1 = __float2int_rn(a.y*sc);
    int q2 = __float2int_rn(a.z*sc), q3 = __float2int_rn(a.w*sc);
    int q4 = __float2int_rn(b.x*sc), q5 = __float2int_rn(b.y*sc);
    int q6 = __float2int_rn(b.z*sc), q7 = __float2int_rn(b.w*sc);
    int lo = (q0 & 255) | ((q1 & 255) << 8) | ((q2 & 255) << 16) | ((q3 & 255) << 24);
    int hi = (q4 & 255) | ((q5 & 255) << 8) | ((q6 & 255) << 16) | ((q7 & 255) << 24);
    ((int2*)(xb + (size_t)row * D_DIM))[lane] = make_int2(lo, hi);
}

// ---- kernel 2: 128x256-tile int8 GEMM + argmax (R15: barrier-free) ---------
// The 4 MB int8 matrix is L2/LLC-resident (FETCH_SIZE 15.8 MB vs 203 MB of
// logical tile reads), and LDS reuse factor was only 2 waves/tile — so LDS
// staging bought bandwidth we don't need while its per-K-step
// vmcnt(0)+barrier drain exposed the full L2 round-trip 4x per block
// (MfmaUtil 14%). R15 loads MFMA fragments straight from global (L2) into
// registers: no As/Bs, no K-loop barriers, fully unrolled 8x(12 loads +
// 32 MFMA) stream the compiler can software-pipeline freely.
// Addressing: loop-invariant 32-bit voffsets (SGPR base + imm k0 <= 448
// folds into the 13-bit offset field). Per load instr the wave reads 16
// fully-packed 64B lines (quad covers the 64B, qr covers 16 rows).
// Coverage schedule unchanged: padded-triangular, bi <= 2bj+1, bi%8 ==
// blockIdx%8 (per-XCD L2 A-band). Diagonal masked in both reductions.
// NOTE (R12-R14): do NOT fuse the neighbor gather into this kernel — every
// variant regressed via occupancy/register cliffs.

__global__ __launch_bounds__(256, 2) void gemm_argmax(
        const unsigned char* __restrict__ X, u64* __restrict__ best) {
    __shared__ u64 rmerge[TM * 2];            // 2 KB
    __shared__ u64 cmerge[TN * 2];            // 4 KB

    // decode padded id: col-group q (4 cols of width-256), per-col cnt 8(q+1)
    int l = blockIdx.x;
    int q = (int)(sqrtf((float)l / 16.0f + 0.25f) - 0.5f);
    while (16 * (q + 1) * (q + 2) <= l) ++q;
    while (16 * q * (q + 1) > l) --q;
    int rrem = l - 16 * q * (q + 1);
    int cw   = 8 * (q + 1);
    int c    = rrem / cw;
    int bi   = rrem - c * cw;           // row tile (128-wide), bi%8 == l%8
    int bj   = 4 * q + c;               // col tile (256-wide)
    if (bi > 2 * bj + 1) return;        // padding / fully-below-diagonal
    const int m0 = bi * TM;
    const int n0 = bj * TN;

    const int t    = threadIdx.x;
    const int lane = t & 63;
    const int w    = t >> 6;
    const int wm   = w >> 1, wn = w & 1;
    const int qr   = lane & 15;
    const int quad = lane >> 4;

    // loop-invariant byte offsets into X (fits 32-bit: 8192*512 = 4 MB)
    int offA[4], offB[8];
    #pragma unroll
    for (int mi = 0; mi < 4; mi++)
        offA[mi] = (m0 + wm * 64 + mi * 16 + qr) * D_DIM + quad * 16;
    #pragma unroll
    for (int ni = 0; ni < 8; ni++)
        offB[ni] = (n0 + wn * 128 + ni * 16 + qr) * D_DIM + quad * 16;

    i32x4 accm[4][8];
    #pragma unroll
    for (int mi = 0; mi < 4; mi++)
        #pragma unroll
        for (int ni = 0; ni < 8; ni++)
            accm[mi][ni] = (i32x4){0, 0, 0, 0};

    #pragma unroll
    for (int k0 = 0; k0 < D_DIM; k0 += 64) {
        i32x4 av[4], bv[8];
        #pragma unroll
        for (int mi = 0; mi < 4; mi++)
            av[mi] = *(const i32x4*)(X + offA[mi] + k0);
        #pragma unroll
        for (int ni = 0; ni < 8; ni++)
            bv[ni] = *(const i32x4*)(X + offB[ni] + k0);
        #pragma unroll
        for (int mi = 0; mi < 4; mi++)
            #pragma unroll
            for (int ni = 0; ni < 8; ni++)
                accm[mi][ni] = __builtin_amdgcn_mfma_i32_16x16x64_i8(
                    av[mi], bv[ni], accm[mi][ni], 0, 0, 0);
    }

    // ---- row-side argmax over this tile's 256 cols (diag masked) ----------
    const int colg_base = n0 + wn * 128 + qr;
    #pragma unroll
    for (int mi = 0; mi < 4; mi++) {
        #pragma unroll
        for (int r = 0; r < 4; r++) {
            const int rowl = wm * 64 + mi * 16 + quad * 4 + r;
            const int rowg = m0 + rowl;
            u64 key = 0ull;
            #pragma unroll
            for (int ni = 0; ni < 8; ni++) {
                int colg = colg_base + ni * 16;
                if (colg == rowg) continue;
                unsigned bd = (unsigned)accm[mi][ni][r] + 0x80000000u;
                u64 k = ((u64)bd << 32) | (u64)(0xFFFFFFFFu - (unsigned)colg);
                key = key > k ? key : k;
            }
            #pragma unroll
            for (int m = 1; m <= 8; m <<= 1) {
                u64 o = shfl_xor_u64(key, m);
                key = key > o ? key : o;
            }
            if (qr == 0) rmerge[rowl * 2 + wn] = key;
        }
    }

    // ---- col-side argmax (symmetry; diag masked here too) ------------------
    #pragma unroll
    for (int ni = 0; ni < 8; ni++) {
        const int colg = colg_base + ni * 16;
        u64 key = 0ull;
        #pragma unroll
        for (int mi = 0; mi < 4; mi++) {
            #pragma unroll
            for (int r = 0; r < 4; r++) {
                int rowg = m0 + wm * 64 + mi * 16 + quad * 4 + r;
                if (rowg == colg) continue;
                unsigned bd = (unsigned)accm[mi][ni][r] + 0x80000000u;
                u64 k = ((u64)bd << 32) | (u64)(0xFFFFFFFFu - (unsigned)rowg);
                key = key > k ? key : k;
            }
        }
        u64 o = shfl_xor_u64(key, 16); key = key > o ? key : o;
        o     = shfl_xor_u64(key, 32); key = key > o ? key : o;
        if (quad == 0) cmerge[(wn * 128 + ni * 16 + qr) * 2 + wm] = key;
    }
    __syncthreads();
    if (t < TM) {
        u64 a = rmerge[t * 2], b = rmerge[t * 2 + 1];
        u64 k = a > b ? a : b;
        atomicMax(&best[m0 + t], k);
    }
    {   // all 256 threads: one column each
        u64 ca = cmerge[t * 2], cb = cmerge[t * 2 + 1];
        u64 ck = ca > cb ? ca : cb;
        atomicMax(&best[n0 + t], ck);
    }
}

// ---- kernel 3: exact fp32 distance + fused mean (256-block cheap ticket) ---

__global__ __launch_bounds__(256) void neighbor_reduce(
        const float* __restrict__ in, const float* __restrict__ inv_norm,
        const u64* __restrict__ best, float* __restrict__ acc,
        int* __restrict__ cnt, float* __restrict__ out, int B) {
    const int wave = threadIdx.x >> 6;
    const int lane = threadIdx.x & 63;
    float lsum = 0.f;
    #pragma unroll
    for (int rr = 0; rr < 8; rr++) {
        const int row = blockIdx.x * 32 + wave * 8 + rr;
        u64 k   = best[row];
        int nbr = (int)(0xFFFFFFFFu - (unsigned)(k & 0xFFFFFFFFull));
        float ir  = inv_norm[row];
        float inb = inv_norm[nbr];
        const float4* rp = (const float4*)(in + (size_t)row * D_DIM) + lane * 2;
        const float4* np = (const float4*)(in + (size_t)nbr * D_DIM) + lane * 2;
        float4 r0 = rp[0], r1 = rp[1], q0 = np[0], q1 = np[1];
        float d0 = r0.x*ir - q0.x*inb + 1e-8f, d1 = r0.y*ir - q0.y*inb + 1e-8f;
        float d2 = r0.z*ir - q0.z*inb + 1e-8f, d3 = r0.w*ir - q0.w*inb + 1e-8f;
        float d4 = r1.x*ir - q1.x*inb + 1e-8f, d5 = r1.y*ir - q1.y*inb + 1e-8f;
        float d6 = r1.z*ir - q1.z*inb + 1e-8f, d7 = r1.w*ir - q1.w*inb + 1e-8f;
        float s = d0*d0 + d1*d1 + d2*d2 + d3*d3 + d4*d4 + d5*d5 + d6*d6 + d7*d7;
        #pragma unroll
        for (int m = 1; m <= 32; m <<= 1) s += __shfl_xor(s, m, 64);
        if (lane == 0) lsum += logf(sqrtf(s) + 1e-8f);
    }
    __shared__ float sb[4];
    if (lane == 0) sb[wave] = lsum;
    __syncthreads();
    if (threadIdx.x == 0) {
        float partial = sb[0] + sb[1] + sb[2] + sb[3];
        atomicAdd(acc, partial);
        __threadfence();
        int done = atomicAdd(cnt, 1);
        if (done == gridDim.x - 1) {
            __threadfence();
            float tot = atomicAdd(acc, 0.0f);   // device-scope read of final sum
            out[0] = -tot / (float)B;
        }
    }
}

// ---- launch ----------------------------------------------------------------

extern "C" void kernel_launch(void* const* d_in, const int* in_sizes, int n_in,
                              void* d_out, int out_size, void* d_ws, size_t ws_size,
                              hipStream_t stream) {
    const float* in = (const float*)d_in[0];
    const int B = in_sizes[0] / D_DIM;          // 8192
    const int nblk = 16 * 8 * 9;                // 1152 padded tiles (8 col-groups)

    char* w = (char*)d_ws;
    unsigned char* xb = (unsigned char*)w;                     // B*D int8
    float* invn = (float*)(w + (size_t)B * D_DIM);
    u64*   best = (u64*)(w + (size_t)B * D_DIM + (size_t)B * 4);
    float* acc  = (float*)(w + (size_t)B * D_DIM + (size_t)B * 4 + (size_t)B * 8);
    int*   cnt  = (int*)(acc + 1);
    float* out  = (float*)d_out;

    normalize_rows<<<B / 4, 256, 0, stream>>>(in, xb, invn, best, acc, cnt);
    gemm_argmax<<<nblk, 256, 0, stream>>>(xb, best);
    neighbor_reduce<<<B / 32, 256, 0, stream>>>(in, invn, best, acc, cnt, out, B);
}

// Round 2
// 121.010 us; speedup vs baseline: 1.3096x; 1.3096x over previous
//
#include <hip/hip_runtime.h>
#include <hip/hip_bf16.h>
#include <math.h>

#define D_DIM 512
#define TM    128
#define TN    256

typedef int i32x4 __attribute__((ext_vector_type(4)));
typedef unsigned long long u64;

// ---- helpers ---------------------------------------------------------------

__device__ inline u64 shfl_xor_u64(u64 x, int m) {
    int lo = __shfl_xor((int)(unsigned)(x & 0xFFFFFFFFull), m, 64);
    int hi = __shfl_xor((int)(unsigned)(x >> 32), m, 64);
    return ((u64)(unsigned)hi << 32) | (u64)(unsigned)lo;
}

__device__ inline void async16(unsigned char* lds, const unsigned char* g) {
    __builtin_amdgcn_global_load_lds(
        (const __attribute__((address_space(1))) void*)g,
        (__attribute__((address_space(3))) void*)lds,
        16, 0, 0);
}

// ---- kernel 1: row L2-normalize -> int8 (x127), init best/acc/cnt ----------

__global__ __launch_bounds__(256) void normalize_rows(
        const float* __restrict__ in, unsigned char* __restrict__ xb,
        float* __restrict__ inv_norm, u64* __restrict__ best,
        float* __restrict__ acc, int* __restrict__ cnt) {
    const int row  = blockIdx.x * 4 + (threadIdx.x >> 6);
    const int lane = threadIdx.x & 63;
    if (blockIdx.x == 0 && threadIdx.x == 0) { acc[0] = 0.f; cnt[0] = 0; }
    const float4* rp = (const float4*)(in + (size_t)row * D_DIM) + lane * 2;
    float4 a = rp[0], b = rp[1];
    float s = a.x*a.x + a.y*a.y + a.z*a.z + a.w*a.w
            + b.x*b.x + b.y*b.y + b.z*b.z + b.w*b.w;
    #pragma unroll
    for (int m = 1; m <= 32; m <<= 1) s += __shfl_xor(s, m, 64);
    float inv = 1.0f / fmaxf(sqrtf(s), 1e-8f);
    if (lane == 0) {
        inv_norm[row] = inv;
        best[row] = 0ull;   // below any real packed key
    }
    float sc = inv * 127.0f;   // int8 symmetric quant; |x_norm|<=1 -> no clamp
    int q0 = __float2int_rn(a.x*sc), q1 = __float2int_rn(a.y*sc);
    int q2 = __float2int_rn(a.z*sc), q3 = __float2int_rn(a.w*sc);
    int q4 = __float2int_rn(b.x*sc), q5 = __float2int_rn(b.y*sc);
    int q6 = __float2int_rn(b.z*sc), q7 = __float2int_rn(b.w*sc);
    int lo = (q0 & 255) | ((q1 & 255) << 8) | ((q2 & 255) << 16) | ((q3 & 255) << 24);
    int hi = (q4 & 255) | ((q5 & 255) << 8) | ((q6 & 255) << 16) | ((q7 & 255) << 24);
    ((int2*)(xb + (size_t)row * D_DIM))[lane] = make_int2(lo, hi);
}

// ---- kernel 2: 128x256-tile int8 GEMM + argmax (R16) -----------------------
// R15 post-mortem: direct global->reg fragment loads exposed per-fragment L2
// latency against the loop-carried MFMA chain (MfmaUtil 6%). LDS staging is
// required; its cost in R11 was the per-K-step vmcnt(0)+barrier DRAIN
// (__syncthreads forces a full drain before s_barrier).
// R16 = T3/T4 minimum 2-phase: BK=64 double-buffered (same 55296 B LDS ->
// 2 blocks/CU kept), stage(t+1) issued before compute(t), counted
// s_waitcnt vmcnt(6) + RAW s_barrier so next-tile loads stay in flight
// across the barrier. 64B-row swizzle: slot = quad ^ ((r>>1)&3) -> per
// 16-lane phase group absolute slot%8 covers all 8 values twice = free
// 2-way. Source pre-swizzled (t&3)^((t>>3)&3) (j-independent: j*32==0 mod 4).
// Pipeline safety: every ds_read feeds an MFMA before the end-of-iter
// barrier => lgkmcnt-drained per wave before the buffer is overwritten.
// NOTE (R12-R14): do NOT fuse the neighbor gather into this kernel.

__global__ __launch_bounds__(256, 2) void gemm_argmax(
        const unsigned char* __restrict__ X, u64* __restrict__ best) {
    __shared__ unsigned char As[2][64 * TM];  // 2 x 8 KB  (128 rows x 64B)
    __shared__ unsigned char Bs[2][64 * TN];  // 2 x 16 KB (256 rows x 64B)
    __shared__ u64 rmerge[TM * 2];            // 2 KB
    __shared__ u64 cmerge[TN * 2];            // 4 KB

    // decode padded id: col-group q (4 cols of width-256), per-col cnt 8(q+1)
    int l = blockIdx.x;
    int q = (int)(sqrtf((float)l / 16.0f + 0.25f) - 0.5f);
    while (16 * (q + 1) * (q + 2) <= l) ++q;
    while (16 * q * (q + 1) > l) --q;
    int rrem = l - 16 * q * (q + 1);
    int cw   = 8 * (q + 1);
    int c    = rrem / cw;
    int bi   = rrem - c * cw;           // row tile (128-wide), bi%8 == l%8
    int bj   = 4 * q + c;               // col tile (256-wide)
    if (bi > 2 * bj + 1) return;        // padding / fully-below-diagonal
    const int m0 = bi * TM;
    const int n0 = bj * TN;

    const int t    = threadIdx.x;
    const int lane = t & 63;
    const int w    = t >> 6;
    const int wm   = w >> 1, wn = w & 1;
    const int qr   = lane & 15;
    const int quad = lane >> 4;

    // staging source: row rS = t>>2 (+j*64), pre-swizzled k-slot
    const int srcsl = ((t & 3) ^ ((t >> 3) & 3)) * 16;
    const unsigned char* gA = X + (size_t)(m0 + (t >> 2)) * D_DIM + srcsl;
    const unsigned char* gB = X + (size_t)(n0 + (t >> 2)) * D_DIM + srcsl;

    #define STAGE(buf, k0)                                            \
        do {                                                          \
            _Pragma("unroll")                                         \
            for (int j = 0; j < 2; j++)                               \
                async16(&As[buf][j * 4096 + t * 16],                  \
                        gA + (size_t)(j * 64) * D_DIM + (k0));        \
            _Pragma("unroll")                                         \
            for (int j = 0; j < 4; j++)                               \
                async16(&Bs[buf][j * 4096 + t * 16],                  \
                        gB + (size_t)(j * 64) * D_DIM + (k0));        \
        } while (0)

    i32x4 accm[4][8];
    #pragma unroll
    for (int mi = 0; mi < 4; mi++)
        #pragma unroll
        for (int ni = 0; ni < 8; ni++)
            accm[mi][ni] = (i32x4){0, 0, 0, 0};

    // fragment read slot (uniform across mi/ni: r>>1 components == 0 mod 4)
    const int rdsl = (quad ^ ((qr >> 1) & 3)) * 16;

    STAGE(0, 0);
    #pragma unroll
    for (int t8 = 0; t8 < 8; t8++) {
        const int cur = t8 & 1;
        if (t8 < 7) {
            STAGE(cur ^ 1, (t8 + 1) * 64);
            asm volatile("s_waitcnt vmcnt(6)" ::: "memory");  // buf[cur] landed
        } else {
            asm volatile("s_waitcnt vmcnt(0)" ::: "memory");
        }
        __builtin_amdgcn_s_barrier();

        i32x4 av[4], bv[8];
        const unsigned char* pA = &As[cur][(wm * 64 + qr) * 64 + rdsl];
        const unsigned char* pB = &Bs[cur][(wn * 128 + qr) * 64 + rdsl];
        #pragma unroll
        for (int mi = 0; mi < 4; mi++)
            av[mi] = *(const i32x4*)(pA + mi * 1024);
        #pragma unroll
        for (int ni = 0; ni < 8; ni++)
            bv[ni] = *(const i32x4*)(pB + ni * 1024);
        #pragma unroll
        for (int mi = 0; mi < 4; mi++)
            #pragma unroll
            for (int ni = 0; ni < 8; ni++)
                accm[mi][ni] = __builtin_amdgcn_mfma_i32_16x16x64_i8(
                    av[mi], bv[ni], accm[mi][ni], 0, 0, 0);

        asm volatile("" ::: "memory");   // keep frag reads above this barrier
        __builtin_amdgcn_s_barrier();    // reads drained (consumed by MFMA);
                                         // safe to overwrite buf[cur] next iter
    }
    #undef STAGE

    // ---- row-side argmax over this tile's 256 cols (diag masked) ----------
    const int colg_base = n0 + wn * 128 + qr;
    #pragma unroll
    for (int mi = 0; mi < 4; mi++) {
        #pragma unroll
        for (int r = 0; r < 4; r++) {
            const int rowl = wm * 64 + mi * 16 + quad * 4 + r;
            const int rowg = m0 + rowl;
            u64 key = 0ull;
            #pragma unroll
            for (int ni = 0; ni < 8; ni++) {
                int colg = colg_base + ni * 16;
                if (colg == rowg) continue;
                unsigned bd = (unsigned)accm[mi][ni][r] + 0x80000000u;
                u64 k = ((u64)bd << 32) | (u64)(0xFFFFFFFFu - (unsigned)colg);
                key = key > k ? key : k;
            }
            #pragma unroll
            for (int m = 1; m <= 8; m <<= 1) {
                u64 o = shfl_xor_u64(key, m);
                key = key > o ? key : o;
            }
            if (qr == 0) rmerge[rowl * 2 + wn] = key;
        }
    }

    // ---- col-side argmax (symmetry; diag masked here too) ------------------
    #pragma unroll
    for (int ni = 0; ni < 8; ni++) {
        const int colg = colg_base + ni * 16;
        u64 key = 0ull;
        #pragma unroll
        for (int mi = 0; mi < 4; mi++) {
            #pragma unroll
            for (int r = 0; r < 4; r++) {
                int rowg = m0 + wm * 64 + mi * 16 + quad * 4 + r;
                if (rowg == colg) continue;
                unsigned bd = (unsigned)accm[mi][ni][r] + 0x80000000u;
                u64 k = ((u64)bd << 32) | (u64)(0xFFFFFFFFu - (unsigned)rowg);
                key = key > k ? key : k;
            }
        }
        u64 o = shfl_xor_u64(key, 16); key = key > o ? key : o;
        o     = shfl_xor_u64(key, 32); key = key > o ? key : o;
        if (quad == 0) cmerge[(wn * 128 + ni * 16 + qr) * 2 + wm] = key;
    }
    __syncthreads();
    if (t < TM) {
        u64 a = rmerge[t * 2], b = rmerge[t * 2 + 1];
        u64 k = a > b ? a : b;
        atomicMax(&best[m0 + t], k);
    }
    {   // all 256 threads: one column each
        u64 ca = cmerge[t * 2], cb = cmerge[t * 2 + 1];
        u64 ck = ca > cb ? ca : cb;
        atomicMax(&best[n0 + t], ck);
    }
}

// ---- kernel 3: exact fp32 distance + fused mean (256-block cheap ticket) ---

__global__ __launch_bounds__(256) void neighbor_reduce(
        const float* __restrict__ in, const float* __restrict__ inv_norm,
        const u64* __restrict__ best, float* __restrict__ acc,
        int* __restrict__ cnt, float* __restrict__ out, int B) {
    const int wave = threadIdx.x >> 6;
    const int lane = threadIdx.x & 63;
    float lsum = 0.f;
    #pragma unroll
    for (int rr = 0; rr < 8; rr++) {
        const int row = blockIdx.x * 32 + wave * 8 + rr;
        u64 k   = best[row];
        int nbr = (int)(0xFFFFFFFFu - (unsigned)(k & 0xFFFFFFFFull));
        float ir  = inv_norm[row];
        float inb = inv_norm[nbr];
        const float4* rp = (const float4*)(in + (size_t)row * D_DIM) + lane * 2;
        const float4* np = (const float4*)(in + (size_t)nbr * D_DIM) + lane * 2;
        float4 r0 = rp[0], r1 = rp[1], q0 = np[0], q1 = np[1];
        float d0 = r0.x*ir - q0.x*inb + 1e-8f, d1 = r0.y*ir - q0.y*inb + 1e-8f;
        float d2 = r0.z*ir - q0.z*inb + 1e-8f, d3 = r0.w*ir - q0.w*inb + 1e-8f;
        float d4 = r1.x*ir - q1.x*inb + 1e-8f, d5 = r1.y*ir - q1.y*inb + 1e-8f;
        float d6 = r1.z*ir - q1.z*inb + 1e-8f, d7 = r1.w*ir - q1.w*inb + 1e-8f;
        float s = d0*d0 + d1*d1 + d2*d2 + d3*d3 + d4*d4 + d5*d5 + d6*d6 + d7*d7;
        #pragma unroll
        for (int m = 1; m <= 32; m <<= 1) s += __shfl_xor(s, m, 64);
        if (lane == 0) lsum += logf(sqrtf(s) + 1e-8f);
    }
    __shared__ float sb[4];
    if (lane == 0) sb[wave] = lsum;
    __syncthreads();
    if (threadIdx.x == 0) {
        float partial = sb[0] + sb[1] + sb[2] + sb[3];
        atomicAdd(acc, partial);
        __threadfence();
        int done = atomicAdd(cnt, 1);
        if (done == gridDim.x - 1) {
            __threadfence();
            float tot = atomicAdd(acc, 0.0f);   // device-scope read of final sum
            out[0] = -tot / (float)B;
        }
    }
}

// ---- launch ----------------------------------------------------------------

extern "C" void kernel_launch(void* const* d_in, const int* in_sizes, int n_in,
                              void* d_out, int out_size, void* d_ws, size_t ws_size,
                              hipStream_t stream) {
    const float* in = (const float*)d_in[0];
    const int B = in_sizes[0] / D_DIM;          // 8192
    const int nblk = 16 * 8 * 9;                // 1152 padded tiles (8 col-groups)

    char* w = (char*)d_ws;
    unsigned char* xb = (unsigned char*)w;                     // B*D int8
    float* invn = (float*)(w + (size_t)B * D_DIM);
    u64*   best = (u64*)(w + (size_t)B * D_DIM + (size_t)B * 4);
    float* acc  = (float*)(w + (size_t)B * D_DIM + (size_t)B * 4 + (size_t)B * 8);
    int*   cnt  = (int*)(acc + 1);
    float* out  = (float*)d_out;

    normalize_rows<<<B / 4, 256, 0, stream>>>(in, xb, invn, best, acc, cnt);
    gemm_argmax<<<nblk, 256, 0, stream>>>(xb, best);
    neighbor_reduce<<<B / 32, 256, 0, stream>>>(in, invn, best, acc, cnt, out, B);
}

// Round 3
// 109.263 us; speedup vs baseline: 1.4504x; 1.1075x over previous
//
#include <hip/hip_runtime.h>
#include <hip/hip_bf16.h>
#include <math.h>

#define D_DIM 512
#define TM    128
#define TN    256

typedef int i32x4 __attribute__((ext_vector_type(4)));
typedef unsigned long long u64;

// ---- helpers ---------------------------------------------------------------

__device__ inline void async16(unsigned char* lds, const unsigned char* g) {
    __builtin_amdgcn_global_load_lds(
        (const __attribute__((address_space(1))) void*)g,
        (__attribute__((address_space(3))) void*)lds,
        16, 0, 0);
}

// ---- kernel 1: row L2-normalize -> int8 (x127), init best/acc/cnt ----------

__global__ __launch_bounds__(256) void normalize_rows(
        const float* __restrict__ in, unsigned char* __restrict__ xb,
        float* __restrict__ inv_norm, u64* __restrict__ best,
        float* __restrict__ acc, int* __restrict__ cnt) {
    const int row  = blockIdx.x * 4 + (threadIdx.x >> 6);
    const int lane = threadIdx.x & 63;
    if (blockIdx.x == 0 && threadIdx.x == 0) { acc[0] = 0.f; cnt[0] = 0; }
    const float4* rp = (const float4*)(in + (size_t)row * D_DIM) + lane * 2;
    float4 a = rp[0], b = rp[1];
    float s = a.x*a.x + a.y*a.y + a.z*a.z + a.w*a.w
            + b.x*b.x + b.y*b.y + b.z*b.z + b.w*b.w;
    #pragma unroll
    for (int m = 1; m <= 32; m <<= 1) s += __shfl_xor(s, m, 64);
    float inv = 1.0f / fmaxf(sqrtf(s), 1e-8f);
    if (lane == 0) {
        inv_norm[row] = inv;
        best[row] = 0ull;   // below any real packed key
    }
    float sc = inv * 127.0f;   // int8 symmetric quant; |x_norm|<=1 -> no clamp
    int q0 = __float2int_rn(a.x*sc), q1 = __float2int_rn(a.y*sc);
    int q2 = __float2int_rn(a.z*sc), q3 = __float2int_rn(a.w*sc);
    int q4 = __float2int_rn(b.x*sc), q5 = __float2int_rn(b.y*sc);
    int q6 = __float2int_rn(b.z*sc), q7 = __float2int_rn(b.w*sc);
    int lo = (q0 & 255) | ((q1 & 255) << 8) | ((q2 & 255) << 16) | ((q3 & 255) << 24);
    int hi = (q4 & 255) | ((q5 & 255) << 8) | ((q6 & 255) << 16) | ((q7 & 255) << 24);
    ((int2*)(xb + (size_t)row * D_DIM))[lane] = make_int2(lo, hi);
}

// ---- kernel 2: 128x256-tile int8 GEMM + argmax (R17) -----------------------
// R15/R16 post-mortem: pipeline variants (drain vs counted-vmcnt) were
// equivalent => the stall was never load latency. Model: u64 epilogue
// (pack/compare/4-round shfl_xor_u64 chains) ~= 7-8K serial cycles/wave,
// MORE than the MFMA phase (5.2K), with only 2 waves/SIMD (128 AGPR acc +
// 124 VGPR ~= 252 combined regs) to hide it. VALUBusy 25% ~= 2x MfmaUtil.
// R17:
//  (a) u32 tile-local keys: |i8 dot| <= 512*127^2 < 2^23, tile-local idx
//      fits 8 bits -> key = (dot+0x800000)<<8 | (255-lidx). Reduction is
//      v_max_u32 + 32-bit shfl (half the ops/latency). Convert to the u64
//      global key only at the per-row atomic. Ordering/tie-break preserved.
//  (b) 8-wave 512-thread blocks, same 128x256 tile: per-wave acc 64 regs,
//      combined pressure ~115 -> __launch_bounds__(512,4) keeps 2 blocks/CU
//      = 16 waves/CU (2x TLP); per-wave epilogue halves.
//  (c) LDS exactly 48K (2x dbuf BK=64), merge arrays (4KB) aliased onto the
//      dead K-loop buffers after the last barrier.
// Swizzle (both-sides, rule #21): LDS[r][c] = G[r][c ^ ((r>>1)&3)] via
// pre-swizzled source slot ((t&3)^((t>>3)&3)); read slot quad^((qr>>1)&3).
// 16 lanes/quad-phase -> 2 lanes/bank = free.
// NOTE (R12-R14): do NOT fuse the neighbor gather into this kernel.

__global__ __launch_bounds__(512, 4) void gemm_argmax(
        const unsigned char* __restrict__ X, u64* __restrict__ best) {
    __shared__ unsigned char smem[49152];
    unsigned char* As0 = smem;                       // [2][8192]  A: 128x64B
    unsigned char* Bs0 = smem + 16384;               // [2][16384] B: 256x64B
    unsigned int* rmerge = (unsigned int*)smem;          // [128][4] 2KB (alias)
    unsigned int* cmerge = (unsigned int*)(smem + 2048); // [256][2] 2KB (alias)

    // decode padded id: col-group q (4 cols of width-256), per-col cnt 8(q+1)
    int l = blockIdx.x;
    int q = (int)(sqrtf((float)l / 16.0f + 0.25f) - 0.5f);
    while (16 * (q + 1) * (q + 2) <= l) ++q;
    while (16 * q * (q + 1) > l) --q;
    int rrem = l - 16 * q * (q + 1);
    int cw   = 8 * (q + 1);
    int c    = rrem / cw;
    int bi   = rrem - c * cw;           // row tile (128-wide), bi%8 == l%8
    int bj   = 4 * q + c;               // col tile (256-wide)
    if (bi > 2 * bj + 1) return;        // padding / fully-below-diagonal
    const int m0 = bi * TM;
    const int n0 = bj * TN;

    const int t    = threadIdx.x;
    const int lane = t & 63;
    const int w    = t >> 6;            // 0..7
    const int wm   = w >> 2;            // row half   (64 rows)
    const int wn   = w & 3;             // col quarter (64 cols)
    const int qr   = lane & 15;
    const int quad = lane >> 4;

    // staging source: row t>>2, pre-swizzled k-slot
    const int srcsl = ((t & 3) ^ ((t >> 3) & 3)) * 16;
    const unsigned char* gA  = X + (size_t)(m0 + (t >> 2)) * D_DIM + srcsl;
    const unsigned char* gB  = X + (size_t)(n0 + (t >> 2)) * D_DIM + srcsl;
    const unsigned char* gB2 = gB + (size_t)128 * D_DIM;

    #define STAGE(buf, k0)                                        \
        do {                                                      \
            async16(As0 + (buf) * 8192 + t * 16, gA + (k0));      \
            async16(Bs0 + (buf) * 16384 + t * 16, gB + (k0));     \
            async16(Bs0 + (buf) * 16384 + 8192 + t * 16, gB2 + (k0)); \
        } while (0)

    i32x4 accm[4][4];
    #pragma unroll
    for (int mi = 0; mi < 4; mi++)
        #pragma unroll
        for (int ni = 0; ni < 4; ni++)
            accm[mi][ni] = (i32x4){0, 0, 0, 0};

    const int rdsl = (quad ^ ((qr >> 1) & 3)) * 16;   // read-side swizzle

    STAGE(0, 0);
    #pragma unroll
    for (int t8 = 0; t8 < 8; t8++) {
        const int cur = t8 & 1;
        if (t8 < 7) {
            STAGE(cur ^ 1, (t8 + 1) * 64);
            asm volatile("s_waitcnt vmcnt(3)" ::: "memory");  // buf[cur] landed
        } else {
            asm volatile("s_waitcnt vmcnt(0)" ::: "memory");
        }
        __builtin_amdgcn_s_barrier();

        i32x4 av[4], bv[4];
        const unsigned char* pA = As0 + cur * 8192  + (wm * 64 + qr) * 64 + rdsl;
        const unsigned char* pB = Bs0 + cur * 16384 + (wn * 64 + qr) * 64 + rdsl;
        #pragma unroll
        for (int mi = 0; mi < 4; mi++)
            av[mi] = *(const i32x4*)(pA + mi * 1024);
        #pragma unroll
        for (int ni = 0; ni < 4; ni++)
            bv[ni] = *(const i32x4*)(pB + ni * 1024);
        #pragma unroll
        for (int mi = 0; mi < 4; mi++)
            #pragma unroll
            for (int ni = 0; ni < 4; ni++)
                accm[mi][ni] = __builtin_amdgcn_mfma_i32_16x16x64_i8(
                    av[mi], bv[ni], accm[mi][ni], 0, 0, 0);

        asm volatile("" ::: "memory");   // keep frag reads above this barrier
        __builtin_amdgcn_s_barrier();    // reads consumed; safe to overwrite
    }
    #undef STAGE

    // ---- epilogue: u32 tile-local keys ------------------------------------
    const int colg_base = n0 + wn * 64 + qr;          // + ni*16

    // row-side argmax over this wave's 64 cols (diag masked)
    #pragma unroll
    for (int mi = 0; mi < 4; mi++) {
        #pragma unroll
        for (int r = 0; r < 4; r++) {
            const int rowl = wm * 64 + mi * 16 + quad * 4 + r;
            const int rowg = m0 + rowl;
            unsigned key = 0u;
            #pragma unroll
            for (int ni = 0; ni < 4; ni++) {
                const int colg = colg_base + ni * 16;
                const unsigned lcol = (unsigned)(wn * 64 + ni * 16 + qr);
                unsigned k = (((unsigned)accm[mi][ni][r] + 0x800000u) << 8)
                           | (255u - lcol);
                k = (colg == rowg) ? 0u : k;
                key = key > k ? key : k;
            }
            #pragma unroll
            for (int m = 1; m <= 8; m <<= 1) {
                unsigned o = (unsigned)__shfl_xor((int)key, m, 64);
                key = key > o ? key : o;
            }
            if (qr == 0) rmerge[rowl * 4 + wn] = key;
        }
    }

    // col-side argmax (symmetry; diag masked here too)
    #pragma unroll
    for (int ni = 0; ni < 4; ni++) {
        const int colg = colg_base + ni * 16;
        unsigned key = 0u;
        #pragma unroll
        for (int mi = 0; mi < 4; mi++) {
            #pragma unroll
            for (int r = 0; r < 4; r++) {
                const unsigned lrow = (unsigned)(wm * 64 + mi * 16 + quad * 4 + r);
                const int rowg = m0 + (int)lrow;
                unsigned k = (((unsigned)accm[mi][ni][r] + 0x800000u) << 8)
                           | (255u - lrow);
                k = (rowg == colg) ? 0u : k;
                key = key > k ? key : k;
            }
        }
        unsigned o = (unsigned)__shfl_xor((int)key, 16, 64);
        key = key > o ? key : o;
        o = (unsigned)__shfl_xor((int)key, 32, 64);
        key = key > o ? key : o;
        if (quad == 0) cmerge[(wn * 64 + ni * 16 + qr) * 2 + wm] = key;
    }
    __syncthreads();

    if (t < TM) {
        unsigned a0 = rmerge[t * 4], a1 = rmerge[t * 4 + 1];
        unsigned a2 = rmerge[t * 4 + 2], a3 = rmerge[t * 4 + 3];
        unsigned k01 = a0 > a1 ? a0 : a1;
        unsigned k23 = a2 > a3 ? a2 : a3;
        unsigned k = k01 > k23 ? k01 : k23;
        // expand to global u64 key: bd32 = dot + 2^31, tie-break smaller col
        unsigned bd32 = (k >> 8) + 0x7F800000u;
        unsigned colg = (unsigned)(n0 + 255) - (k & 255u);
        u64 kk = ((u64)bd32 << 32) | (u64)(0xFFFFFFFFu - colg);
        atomicMax(&best[m0 + t], kk);
    }
    if (t < TN) {
        unsigned c0 = cmerge[t * 2], c1 = cmerge[t * 2 + 1];
        unsigned k = c0 > c1 ? c0 : c1;
        unsigned bd32 = (k >> 8) + 0x7F800000u;
        unsigned rowg = (unsigned)(m0 + 255) - (k & 255u);
        u64 kk = ((u64)bd32 << 32) | (u64)(0xFFFFFFFFu - rowg);
        atomicMax(&best[n0 + t], kk);
    }
}

// ---- kernel 3: exact fp32 distance + fused mean (256-block cheap ticket) ---

__global__ __launch_bounds__(256) void neighbor_reduce(
        const float* __restrict__ in, const float* __restrict__ inv_norm,
        const u64* __restrict__ best, float* __restrict__ acc,
        int* __restrict__ cnt, float* __restrict__ out, int B) {
    const int wave = threadIdx.x >> 6;
    const int lane = threadIdx.x & 63;
    float lsum = 0.f;
    #pragma unroll
    for (int rr = 0; rr < 8; rr++) {
        const int row = blockIdx.x * 32 + wave * 8 + rr;
        u64 k   = best[row];
        int nbr = (int)(0xFFFFFFFFu - (unsigned)(k & 0xFFFFFFFFull));
        float ir  = inv_norm[row];
        float inb = inv_norm[nbr];
        const float4* rp = (const float4*)(in + (size_t)row * D_DIM) + lane * 2;
        const float4* np = (const float4*)(in + (size_t)nbr * D_DIM) + lane * 2;
        float4 r0 = rp[0], r1 = rp[1], q0 = np[0], q1 = np[1];
        float d0 = r0.x*ir - q0.x*inb + 1e-8f, d1 = r0.y*ir - q0.y*inb + 1e-8f;
        float d2 = r0.z*ir - q0.z*inb + 1e-8f, d3 = r0.w*ir - q0.w*inb + 1e-8f;
        float d4 = r1.x*ir - q1.x*inb + 1e-8f, d5 = r1.y*ir - q1.y*inb + 1e-8f;
        float d6 = r1.z*ir - q1.z*inb + 1e-8f, d7 = r1.w*ir - q1.w*inb + 1e-8f;
        float s = d0*d0 + d1*d1 + d2*d2 + d3*d3 + d4*d4 + d5*d5 + d6*d6 + d7*d7;
        #pragma unroll
        for (int m = 1; m <= 32; m <<= 1) s += __shfl_xor(s, m, 64);
        if (lane == 0) lsum += logf(sqrtf(s) + 1e-8f);
    }
    __shared__ float sb[4];
    if (lane == 0) sb[wave] = lsum;
    __syncthreads();
    if (threadIdx.x == 0) {
        float partial = sb[0] + sb[1] + sb[2] + sb[3];
        atomicAdd(acc, partial);
        __threadfence();
        int done = atomicAdd(cnt, 1);
        if (done == gridDim.x - 1) {
            __threadfence();
            float tot = atomicAdd(acc, 0.0f);   // device-scope read of final sum
            out[0] = -tot / (float)B;
        }
    }
}

// ---- launch ----------------------------------------------------------------

extern "C" void kernel_launch(void* const* d_in, const int* in_sizes, int n_in,
                              void* d_out, int out_size, void* d_ws, size_t ws_size,
                              hipStream_t stream) {
    const float* in = (const float*)d_in[0];
    const int B = in_sizes[0] / D_DIM;          // 8192
    const int nblk = 16 * 8 * 9;                // 1152 padded tiles (8 col-groups)

    char* w = (char*)d_ws;
    unsigned char* xb = (unsigned char*)w;                     // B*D int8
    float* invn = (float*)(w + (size_t)B * D_DIM);
    u64*   best = (u64*)(w + (size_t)B * D_DIM + (size_t)B * 4);
    float* acc  = (float*)(w + (size_t)B * D_DIM + (size_t)B * 4 + (size_t)B * 8);
    int*   cnt  = (int*)(acc + 1);
    float* out  = (float*)d_out;

    normalize_rows<<<B / 4, 256, 0, stream>>>(in, xb, invn, best, acc, cnt);
    gemm_argmax<<<nblk, 512, 0, stream>>>(xb, best);
    neighbor_reduce<<<B / 32, 256, 0, stream>>>(in, invn, best, acc, cnt, out, B);
}